// Round 16
// baseline (226.843 us; speedup 1.0000x reference)
//
#include <hip/hip_runtime.h>
#include <math.h>

#define BB 128
#define SS 200
#define MM 50
#define DKK 64
#define DVV 128
#define FF 64
#define NROW (BB*SS)   // 25600

#define WROW 64        // w padded layout: 64 floats/row, m<50 valid, rest zero
#define NFCB (NROW/64) // 400 k_fc blocks
#define WLDS 136       // k_pre/ea LDS bf16 row stride (2-way bank alias = free)
#define FLDS 200       // k_fc LDS bf16 read_w row stride (192+8)
#define CLEN 25        // scan: steps per t-chunk (8 chunks x 25 = 200)
#define MH 25          // scan: m-slots per thread (half of 50)
#define NSCB 100       // scores blocks inside k_pre (256 items each)
#define NEAB 100       // ea blocks inside k_pre (256 rows each)

// workspace layout (floats)
#define W_OFF   0L
#define EA_OFF  (W_OFF + (long)NROW*WROW)        // interleaved (e,a) float2
#define R_OFF   (EA_OFF + (long)NROW*DVV*2)
#define ACC_OFF (R_OFF + (long)NROW*DVV)         // [0]=bce [1]=cnt [2]=counter bits

typedef __attribute__((ext_vector_type(8))) short bf16x8;   // 8 bf16 (4 VGPRs)
typedef __attribute__((ext_vector_type(4))) float f32x4;

__device__ __forceinline__ float rlane(float v, int l) {
    return __builtin_bit_cast(float, __builtin_amdgcn_readlane(__builtin_bit_cast(unsigned, v), l));
}
__device__ __forceinline__ short f2bf(float f) {   // RNE fp32->bf16
    unsigned u = __builtin_bit_cast(unsigned, f);
    u += 0x7fff + ((u >> 16) & 1);
    return (short)(u >> 16);
}
__device__ __forceinline__ bf16x8 cvt8(const float* p) {
    float4 lo = *(const float4*)p;
    float4 hi = *(const float4*)(p + 4);
    bf16x8 f;
    f[0] = f2bf(lo.x); f[1] = f2bf(lo.y); f[2] = f2bf(lo.z); f[3] = f2bf(lo.w);
    f[4] = f2bf(hi.x); f[5] = f2bf(hi.y); f[6] = f2bf(hi.z); f[7] = f2bf(hi.w);
    return f;
}

// ---------------- Kernel 1: fused scores + ea ----------------
// blocks [0,100): softmax scores, 256 items each. blocks [100,200): ea GEMM, 256 rows each.
__global__ __launch_bounds__(256) void k_pre(const int* __restrict__ q_data,
                                             const float* __restrict__ q_embed_w,
                                             const float* __restrict__ mem_key,
                                             const int* __restrict__ qa_data,
                                             const float* __restrict__ qa_embed_w,
                                             const float* __restrict__ erase_w,
                                             const float* __restrict__ erase_b,
                                             const float* __restrict__ add_w,
                                             const float* __restrict__ add_b,
                                             float* __restrict__ w_out,
                                             float* __restrict__ EA,
                                             float* __restrict__ acc) {
    __shared__ union {
        short  wl[2 * 128 * WLDS];   // ea branch: bf16 weights, 69.6 KB
        float4 mk[MM * 16];          // scores branch: mem_key, 12.8 KB
    } sh;
    int tid = threadIdx.x;
    int bid = blockIdx.x;

    if (bid < NSCB) {
        // ---------- scores branch ----------
        if (bid == 0 && tid == 0) {
            acc[0] = 0.f; acc[1] = 0.f;
            ((unsigned*)acc)[2] = 0u;
        }
        const float4* mkg = (const float4*)mem_key;
        for (int i = tid; i < MM * 16; i += 256) sh.mk[i] = mkg[i];
        __syncthreads();

        int item = bid * 256 + tid;
        int qidx = q_data[item];
        const float4* qg = (const float4*)(q_embed_w + (long)qidx * DKK);
        float4 q[16];
#pragma unroll
        for (int i = 0; i < 16; i++) q[i] = qg[i];

        float s[MM];
        float mx = -1e30f;
#pragma unroll 2
        for (int m = 0; m < MM; m++) {
            float a = 0.f;
#pragma unroll
            for (int k4 = 0; k4 < 16; k4++) {
                float4 mkv = sh.mk[m * 16 + k4];
                float4 qv = q[k4];
                a = fmaf(qv.x, mkv.x, a);
                a = fmaf(qv.y, mkv.y, a);
                a = fmaf(qv.z, mkv.z, a);
                a = fmaf(qv.w, mkv.w, a);
            }
            s[m] = a;
            mx = fmaxf(mx, a);
        }
        float sum = 0.f;
#pragma unroll
        for (int m = 0; m < MM; m++) { s[m] = expf(s[m] - mx); sum += s[m]; }
        float inv = 1.f / sum;

        float* wo = w_out + (long)item * WROW;
#pragma unroll
        for (int m = 0; m < MM; m++) wo[m] = s[m] * inv;
#pragma unroll
        for (int m = MM; m < WROW; m++) wo[m] = 0.f;
        return;
    }

    // ---------- ea branch: 256 rows per block (staging amortized 4x) ----------
    int r0 = (bid - NSCB) * 256;
    int lane = tid & 63;
    int wv = tid >> 6;          // wave 0..3
    int n = lane & 15;
    int quad = lane >> 4;       // 0..3

    for (int i = tid; i < 8192; i += 256) {
        int mat = i >> 12;
        int r = (i >> 5) & 127;
        int p = i & 31;
        float4 src = *(const float4*)((mat ? add_w : erase_w) + r * 128 + p * 4);
        short4 d;
        d.x = f2bf(src.x); d.y = f2bf(src.y); d.z = f2bf(src.z); d.w = f2bf(src.w);
        *(short4*)(sh.wl + (mat * 128 + r) * WLDS + p * 4) = d;
    }

    // A-frags for 4 row-tiles: row = r0 + rt*64 + wv*16 + n
    bf16x8 afrag[4][4];
#pragma unroll
    for (int rt = 0; rt < 4; rt++) {
        int arow = r0 + rt * 64 + wv * 16 + n;
        int qidx = qa_data[arow];
        const float* qp = qa_embed_w + (long)qidx * DVV + quad * 8;
#pragma unroll
        for (int kb = 0; kb < 4; kb++) afrag[rt][kb] = cvt8(qp + kb * 32);
    }

    float eb_[8], ab_[8];
#pragma unroll
    for (int vt = 0; vt < 8; vt++) {
        eb_[vt] = erase_b[vt * 16 + n];
        ab_[vt] = add_b[vt * 16 + n];
    }
    __syncthreads();

#pragma unroll 1
    for (int vt = 0; vt < 8; vt++) {
        int vrow = vt * 16 + n;
        f32x4 ae[4], aa[4];
#pragma unroll
        for (int rt = 0; rt < 4; rt++) {
            ae[rt] = (f32x4){0.f, 0.f, 0.f, 0.f};
            aa[rt] = (f32x4){0.f, 0.f, 0.f, 0.f};
        }
#pragma unroll
        for (int kb = 0; kb < 4; kb++) {
            bf16x8 be = *(const bf16x8*)(sh.wl + vrow * WLDS + kb * 32 + quad * 8);
            bf16x8 ba = *(const bf16x8*)(sh.wl + (128 + vrow) * WLDS + kb * 32 + quad * 8);
#pragma unroll
            for (int rt = 0; rt < 4; rt++) {
                ae[rt] = __builtin_amdgcn_mfma_f32_16x16x32_bf16(afrag[rt][kb], be, ae[rt], 0, 0, 0);
                aa[rt] = __builtin_amdgcn_mfma_f32_16x16x32_bf16(afrag[rt][kb], ba, aa[rt], 0, 0, 0);
            }
        }
        int v = vt * 16 + n;
        float eb = eb_[vt], ab = ab_[vt];
#pragma unroll
        for (int rt = 0; rt < 4; rt++) {
            int rowbase = r0 + rt * 64 + wv * 16 + quad * 4;
#pragma unroll
            for (int r = 0; r < 4; r++) {
                float ev = 1.f / (1.f + __expf(-(ae[rt][r] + eb)));
                float av = 2.f / (1.f + __expf(-2.f * (aa[rt][r] + ab))) - 1.f;
                float2 o; o.x = ev; o.y = av;
                *(float2*)(EA + (((long)(rowbase + r)) * DVV + v) * 2) = o;
            }
        }
    }
}

// ---------------- Kernel 2: scan — 8 t-chunks x 2 m-halves, 16 waves, (1024,1) ----------------
// R10 structure, spill fixed: VGPR cap 128 (was 64 with (1024,4)). 4 waves/SIMD.
// tc = wave>>1 (t-chunk of 25), mh = wave&1 (m-half of 25, wave-uniform -> readlane legal).
// rd halves combined through LDS (one barrier at end of pass 2).
__global__ __launch_bounds__(1024, 1) void k_scan(const float* __restrict__ w_pad,
                                                  const float* __restrict__ EA,
                                                  const float* __restrict__ init_mv,
                                                  float* __restrict__ R) {
    __shared__ float Sb[MM * 64];            // 12.8 KB boundary states
    __shared__ float Rp[8 * CLEN * 64];      // 51.2 KB rd partials (mh=0)
    int b   = blockIdx.x >> 1;
    int vh  = blockIdx.x & 1;
    int tid = threadIdx.x;
    int lane = tid & 63;
    int wave = tid >> 6;               // 0..15
    int tc = wave >> 1;                // 0..7
    int mh = wave & 1;                 // 0..1 (wave-uniform)
    int v  = vh * 64 + lane;
    int t0 = tc * CLEN;
    int mbase = mh * MH;

    const float* wbase = w_pad + ((long)b * SS + t0) * WROW;
    const float* eab   = EA + (((long)b * SS + t0) * DVV + v) * 2;
    float*       Rb    = R + ((long)b * SS + t0) * DVV + v;

    // ---- pass 1: compose chunk affine map for this thread's 25 m-slots ----
    float A[MH], Bc[MH];
#pragma unroll
    for (int j = 0; j < MH; j++) { A[j] = 1.f; Bc[j] = 0.f; }

    float  w_cur  = wbase[lane];
    float2 ea_cur = *(const float2*)eab;
#pragma unroll 1
    for (int t = 0; t < CLEN; t++) {
        int tp = (t + 1 < CLEN) ? t + 1 : t;
        float  w_nxt  = wbase[tp * WROW + lane];
        float2 ea_nxt = *(const float2*)(eab + (long)tp * DVV * 2);
        float e = ea_cur.x, a = ea_cur.y;
#pragma unroll
        for (int j = 0; j < MH; j++) {
            float wm = rlane(w_cur, mbase + j);
            float alpha = fmaf(-wm, e, 1.f);
            A[j] *= alpha;
            Bc[j] = fmaf(alpha, Bc[j], wm * a);
        }
        w_cur = w_nxt; ea_cur = ea_nxt;
    }

    // ---- combine: serial over t-chunks; both m-halves in parallel ----
    float Mv[MH];
    if (tc == 0) {
#pragma unroll
        for (int j = 0; j < MH; j++) Mv[j] = init_mv[(mbase + j) * DVV + v];
#pragma unroll
        for (int j = 0; j < MH; j++) Sb[(mbase + j) * 64 + lane] = fmaf(A[j], Mv[j], Bc[j]);
    }
    __syncthreads();
    for (int c = 1; c < 8; c++) {
        if (tc == c) {
#pragma unroll
            for (int j = 0; j < MH; j++) Mv[j] = Sb[(mbase + j) * 64 + lane];
            if (c < 7) {
#pragma unroll
                for (int j = 0; j < MH; j++) Sb[(mbase + j) * 64 + lane] = fmaf(A[j], Mv[j], Bc[j]);
            }
        }
        __syncthreads();
    }

    // ---- pass 2: replay chunk; rd halves combine via LDS ----
    w_cur  = wbase[lane];
    ea_cur = *(const float2*)eab;
    float rdbuf[CLEN];
#pragma unroll 1
    for (int t = 0; t < CLEN; t++) {
        int tp = (t + 1 < CLEN) ? t + 1 : t;
        float  w_nxt  = wbase[tp * WROW + lane];
        float2 ea_nxt = *(const float2*)(eab + (long)tp * DVV * 2);
        float e = ea_cur.x, a = ea_cur.y;
        float rd = 0.f;
#pragma unroll
        for (int j = 0; j < MH; j++) {
            float wm = rlane(w_cur, mbase + j);
            rd = fmaf(wm, Mv[j], rd);                // read uses PRE-update Mv
            float alpha = fmaf(-wm, e, 1.f);
            Mv[j] = fmaf(alpha, Mv[j], wm * a);
        }
        if (mh == 0) Rp[(tc * CLEN + t) * 64 + lane] = rd;
        else         rdbuf[t] = rd;
        w_cur = w_nxt; ea_cur = ea_nxt;
    }
    __syncthreads();
    if (mh == 1) {
#pragma unroll
        for (int t = 0; t < CLEN; t++)
            Rb[t * DVV] = rdbuf[t] + Rp[(tc * CLEN + t) * 64 + lane];
    }
}

// ---------------- Kernel 3: FC head via bf16 MFMA + BCE + fused loss ----------------
__global__ __launch_bounds__(256) void k_fc(const float* __restrict__ Rr,
                                            const int* __restrict__ q_data,
                                            const float* __restrict__ q_embed_w,
                                            const float* __restrict__ read_w,
                                            const float* __restrict__ read_b,
                                            const float* __restrict__ pred_w,
                                            const float* __restrict__ pred_b,
                                            const float* __restrict__ target,
                                            float* __restrict__ out,
                                            float* __restrict__ acc) {
    __shared__ short Wl[64 * FLDS];   // 25.6 KB
    __shared__ float2 red[4];
    int tid = threadIdx.x;
    int r0 = blockIdx.x * 64;
    int lane = tid & 63;
    int wv = tid >> 6;          // wave 0..3
    int n = lane & 15;
    int quad = lane >> 4;       // 0..3

    for (int i = tid; i < 3072; i += 256) {
        int f = i / 48, p = i - f * 48;
        float4 src = *(const float4*)(read_w + f * 192 + p * 4);
        short4 d;
        d.x = f2bf(src.x); d.y = f2bf(src.y); d.z = f2bf(src.z); d.w = f2bf(src.w);
        *(short4*)(Wl + f * FLDS + p * 4) = d;
    }

    int arow = r0 + wv * 16 + n;
    const float* rp = Rr + (long)arow * DVV + quad * 8;
    int qi = q_data[arow];
    const float* qp = q_embed_w + (long)qi * DKK + quad * 8;
    bf16x8 afrag[6];
#pragma unroll
    for (int kb = 0; kb < 4; kb++) afrag[kb] = cvt8(rp + kb * 32);
#pragma unroll
    for (int kb = 0; kb < 2; kb++) afrag[4 + kb] = cvt8(qp + kb * 32);

    float rb_[4], pw_[4];
#pragma unroll
    for (int ft = 0; ft < 4; ft++) {
        rb_[ft] = read_b[ft * 16 + n];
        pw_[ft] = pred_w[ft * 16 + n];
    }
    float pb = pred_b[0];
    __syncthreads();

    int rowbase = r0 + wv * 16 + quad * 4;
    float pv[4] = {0.f, 0.f, 0.f, 0.f};
#pragma unroll
    for (int ft = 0; ft < 4; ft++) {
        int f = ft * 16 + n;
        f32x4 ac = {0.f, 0.f, 0.f, 0.f};
#pragma unroll
        for (int kb = 0; kb < 6; kb++) {
            bf16x8 bfr = *(const bf16x8*)(Wl + f * FLDS + kb * 32 + quad * 8);
            ac = __builtin_amdgcn_mfma_f32_16x16x32_bf16(afrag[kb], bfr, ac, 0, 0, 0);
        }
        float rb = rb_[ft], pw = pw_[ft];
#pragma unroll
        for (int r = 0; r < 4; r++) {
            float h = 2.f / (1.f + __expf(-2.f * (ac[r] + rb))) - 1.f;   // tanh
            pv[r] = fmaf(pw, h, pv[r]);
        }
    }

    float bce_sum = 0.f, cnt = 0.f;
#pragma unroll
    for (int r = 0; r < 4; r++) {
        float p = pv[r];
        p += __shfl_xor(p, 1, 64);
        p += __shfl_xor(p, 2, 64);
        p += __shfl_xor(p, 4, 64);
        p += __shfl_xor(p, 8, 64);
        if (n == 0) {
            int row = rowbase + r;
            float tgt = target[row];
            float logit = p + pb;
            float prob = 0.f;
            if (tgt >= 0.f) {
                prob = 1.f / (1.f + __expf(-logit));
                float bce = fmaxf(logit, 0.f) - logit * tgt + log1pf(__expf(-fabsf(logit)));
                bce_sum += bce;
                cnt += 1.f;
            }
            out[1 + row] = prob;
        }
    }
    bce_sum += __shfl_xor(bce_sum, 16, 64);
    bce_sum += __shfl_xor(bce_sum, 32, 64);
    cnt     += __shfl_xor(cnt, 16, 64);
    cnt     += __shfl_xor(cnt, 32, 64);
    if (lane == 0) { red[wv].x = bce_sum; red[wv].y = cnt; }
    __syncthreads();
    if (tid == 0) {
        float bsum = red[0].x + red[1].x + red[2].x + red[3].x;
        float csum = red[0].y + red[1].y + red[2].y + red[3].y;
        atomicAdd(&acc[0], bsum);
        atomicAdd(&acc[1], csum);
        __threadfence();
        unsigned prev = atomicAdd((unsigned*)acc + 2, 1u);
        if (prev == NFCB - 1) {
            __threadfence();
            float B = atomicAdd(&acc[0], 0.f);
            float C = atomicAdd(&acc[1], 0.f);
            out[0] = B / fmaxf(C, 1.f);
        }
    }
}

extern "C" void kernel_launch(void* const* d_in, const int* in_sizes, int n_in,
                              void* d_out, int out_size, void* d_ws, size_t ws_size,
                              hipStream_t stream) {
    const int*   q_data     = (const int*)d_in[0];
    const int*   qa_data    = (const int*)d_in[1];
    const float* target     = (const float*)d_in[2];
    const float* q_embed_w  = (const float*)d_in[3];
    const float* qa_embed_w = (const float*)d_in[4];
    const float* mem_key    = (const float*)d_in[5];
    const float* init_mv    = (const float*)d_in[6];
    const float* erase_w    = (const float*)d_in[7];
    const float* erase_b    = (const float*)d_in[8];
    const float* add_w      = (const float*)d_in[9];
    const float* add_b      = (const float*)d_in[10];
    const float* read_w     = (const float*)d_in[11];
    const float* read_b     = (const float*)d_in[12];
    const float* pred_w     = (const float*)d_in[13];
    const float* pred_b     = (const float*)d_in[14];
    float* out = (float*)d_out;
    float* ws  = (float*)d_ws;

    float* w_all = ws + W_OFF;
    float* EA    = ws + EA_OFF;
    float* R     = ws + R_OFF;
    float* acc   = ws + ACC_OFF;

    k_pre<<<NSCB + NEAB, 256, 0, stream>>>(q_data, q_embed_w, mem_key,
                                           qa_data, qa_embed_w,
                                           erase_w, erase_b, add_w, add_b,
                                           w_all, EA, acc);
    k_scan<<<BB * 2, 1024, 0, stream>>>(w_all, EA, init_mv, R);
    k_fc<<<NFCB, 256, 0, stream>>>(R, q_data, q_embed_w, read_w, read_b,
                                   pred_w, pred_b, target, out, acc);
}